// Round 1
// 898.245 us; speedup vs baseline: 1.1867x; 1.1867x over previous
//
#include <hip/hip_runtime.h>
#include <hip/hip_bf16.h>

typedef __attribute__((ext_vector_type(8))) short bf16x8;   // 8 bf16 = 4 VGPRs (MFMA A/B frag)
typedef __attribute__((ext_vector_type(4))) float f32x4;    // MFMA C/D frag
typedef __attribute__((ext_vector_type(4))) _Float16 f16x4; // 8 B gather unit
typedef unsigned short ushort_t;

#define NN   100000
#define NE   3200000
#define IND  512
#define HIDD 256
#define OUTD 64

#define NBKT 98            // buckets of 1024 nodes: ceil(100000/1024)=98
#define P1E  2048          // edges per phase-1 block

// bf16 helpers (RTNE, manual bit math — no NaN inputs in this problem)
__device__ __forceinline__ ushort_t f2bf(float a) {
    unsigned u = __float_as_uint(a);
    unsigned r = (u + 0x7FFFu + ((u >> 16) & 1u)) >> 16;
    return (ushort_t)r;
}
__device__ __forceinline__ float bf2f(ushort_t b) {
    return __uint_as_float(((unsigned)b) << 16);
}

union U8 { ushort_t us[8]; unsigned u32[4]; uint4 v; };
union U4 { ushort_t us[4]; uint2 v; };

// async global->LDS, 16 B per lane (linear LDS dest = base + lane*16)
#define GLOAD_LDS16(gp, lp) \
    __builtin_amdgcn_global_load_lds( \
        (const __attribute__((address_space(1))) void*)(const void*)(gp), \
        (__attribute__((address_space(3))) void*)(void*)(lp), 16, 0, 0)

// ------------------------------------------------- weight transpose + hi/lo split
__global__ void splitw_k(const float* __restrict__ in, ushort_t* __restrict__ thi,
                         ushort_t* __restrict__ tlo, int R, int C) {
    int i = blockIdx.x * 256 + threadIdx.x;
    if (i < R * C) {
        int r = i / C, c = i % C;
        float a = in[i];
        ushort_t h = f2bf(a);
        thi[(size_t)c * R + r] = h;
        tlo[(size_t)c * R + r] = f2bf(a - bf2f(h));
    }
}

// ------------------------------------------------- layer-1 GEMM: S1 = x @ W1 (fp16 out)
// m97-style: global_load_lds staging (no ds_writes), single LDS buffer, 2 barriers/k-step.
// A stays f32 in LDS; hi/lo split happens in registers after ds_read (trunc hi, trunc lo
// via v_perm — residual error <= 2^-16 rel, far below the fp16 S1 table's 2^-12).
// Both LDS tiles XOR-swizzled on source AND read (rule 21) -> 2-way (free) bank pattern.
// 128x128 tile, wave=64x64 (acc[4][4]), 3 blocks/CU.
__global__ __launch_bounds__(256, 3) void gemm1_k(
    const float* __restrict__ A, const ushort_t* __restrict__ BtHi,
    const ushort_t* __restrict__ BtLo, _Float16* __restrict__ C)
{
    const int M = NN, N = HIDD, K = IND;
    __shared__ __align__(16) float    sA [128 * 32];   // 16 KiB, swizzled
    __shared__ __align__(16) ushort_t sBh[128 * 32];   // 8 KiB, swizzled
    __shared__ __align__(16) ushort_t sBl[128 * 32];   // 8 KiB

    const int tid  = threadIdx.x;
    const int wave = tid >> 6;
    const int lane = tid & 63;
    const int quad = lane >> 4;
    const int l15  = lane & 15;
    const int wr   = wave >> 1;          // 0..1 (row half)
    const int wc   = wave & 1;           // 0..1 (col half)
    const int n0   = blockIdx.x * 128;   // x-fast: both n-blocks of an m-panel adjacent
    const int m0   = blockIdx.y * 128;

    // ---- staging descriptors (k0-invariant). A: 128 rows x 32 f32, 16B-block
    // swizzle blk' = blk ^ ((r&3)<<1) ^ ((r>>2)&1) applied to the GLOBAL source.
    const float* aSrc[4];
    float*       aDst[4];
    #pragma unroll
    for (int it = 0; it < 4; ++it) {
        int f = it * 256 + tid;          // 16B block 0..1023
        int r = f >> 3;                  // 8 blocks per row
        int bp = (f & 7) ^ ((r & 3) << 1) ^ ((r >> 2) & 1);
        int gr = m0 + r; if (gr >= M) gr = M - 1;   // clamp; results row-guarded on store
        aSrc[it] = A + (size_t)gr * K + bp * 4;
        aDst[it] = &sA[f * 4];
    }
    // B: 128 rows (cols of C) x 32 bf16, block swizzle q' = q ^ ((r>>1)&3)
    const ushort_t* bhSrc[2]; const ushort_t* blSrc[2];
    ushort_t* bhDst[2]; ushort_t* blDst[2];
    #pragma unroll
    for (int it = 0; it < 2; ++it) {
        int f = it * 256 + tid;          // block 0..511
        int r = f >> 2;                  // 4 blocks per row
        int qp = (f & 3) ^ ((r >> 1) & 3);
        bhSrc[it] = BtHi + (size_t)(n0 + r) * K + qp * 8;
        blSrc[it] = BtLo + (size_t)(n0 + r) * K + qp * 8;
        bhDst[it] = &sBh[f * 8];
        blDst[it] = &sBl[f * 8];
    }

    // ---- fragment read offsets with the matching read-side swizzle
    int aOff[4][2];
    #pragma unroll
    for (int ms = 0; ms < 4; ++ms) {
        int rA = wr * 64 + ms * 16 + l15;
        int sw = ((rA & 3) << 1) ^ ((rA >> 2) & 1);
        int cb = quad << 1;
        aOff[ms][0] = rA * 32 + (((cb    ) ^ sw) << 2);
        aOff[ms][1] = rA * 32 + (((cb | 1) ^ sw) << 2);
    }
    int bOff[4];
    #pragma unroll
    for (int ns = 0; ns < 4; ++ns) {
        int rB = wc * 64 + ns * 16 + l15;
        bOff[ns] = rB * 32 + (quad ^ ((rB >> 1) & 3)) * 8;
    }

    f32x4 acc[4][4] = {};

    for (int k0 = 0; k0 < K; k0 += 32) {
        #pragma unroll
        for (int it = 0; it < 4; ++it) GLOAD_LDS16(aSrc[it] + k0, aDst[it]);
        #pragma unroll
        for (int it = 0; it < 2; ++it) {
            GLOAD_LDS16(bhSrc[it] + k0, bhDst[it]);
            GLOAD_LDS16(blSrc[it] + k0, blDst[it]);
        }
        __syncthreads();

        // A fragments: read f32, split to hi/lo bf16 in registers.
        // hi = truncate (exactly representable; lo compensates), lo = truncate.
        // v_perm packs two elements per op.
        bf16x8 aH[4], aL[4];
        #pragma unroll
        for (int ms = 0; ms < 4; ++ms) {
            float4 v0 = *(const float4*)&sA[aOff[ms][0]];
            float4 v1 = *(const float4*)&sA[aOff[ms][1]];
            float vv[8] = {v0.x, v0.y, v0.z, v0.w, v1.x, v1.y, v1.z, v1.w};
            U8 H, L;
            #pragma unroll
            for (int j = 0; j < 4; ++j) {
                unsigned u0 = __float_as_uint(vv[2 * j]);
                unsigned u1 = __float_as_uint(vv[2 * j + 1]);
                H.u32[j] = __builtin_amdgcn_perm(u1, u0, 0x07060302u);
                float r0 = vv[2 * j]     - __uint_as_float(u0 & 0xFFFF0000u);
                float r1 = vv[2 * j + 1] - __uint_as_float(u1 & 0xFFFF0000u);
                L.u32[j] = __builtin_amdgcn_perm(__float_as_uint(r1),
                                                 __float_as_uint(r0), 0x07060302u);
            }
            aH[ms] = *(const bf16x8*)&H.v;
            aL[ms] = *(const bf16x8*)&L.v;
        }

        #pragma unroll
        for (int ns = 0; ns < 4; ++ns) {
            bf16x8 bH = *(const bf16x8*)&sBh[bOff[ns]];
            bf16x8 bL = *(const bf16x8*)&sBl[bOff[ns]];
            #pragma unroll
            for (int ms = 0; ms < 4; ++ms) {
                acc[ms][ns] = __builtin_amdgcn_mfma_f32_16x16x32_bf16(aH[ms], bH, acc[ms][ns], 0, 0, 0);
                acc[ms][ns] = __builtin_amdgcn_mfma_f32_16x16x32_bf16(aL[ms], bH, acc[ms][ns], 0, 0, 0);
                acc[ms][ns] = __builtin_amdgcn_mfma_f32_16x16x32_bf16(aH[ms], bL, acc[ms][ns], 0, 0, 0);
            }
        }
        __syncthreads();
    }

    #pragma unroll
    for (int ms = 0; ms < 4; ++ms) {
        int row = m0 + wr * 64 + ms * 16 + quad * 4;
        #pragma unroll
        for (int ns = 0; ns < 4; ++ns) {
            int col = n0 + wc * 64 + ns * 16 + l15;
            #pragma unroll
            for (int r = 0; r < 4; ++r)
                if (row + r < M) C[(size_t)(row + r) * N + col] = (_Float16)acc[ms][ns][r];
        }
    }
}

// ------------------------------------------------- layer-2 GEMM: S2 = h @ W2 (fp16 out)
// A arrives PRE-SPLIT (hHi/hLo bf16, written by spmm_relu) -> pure bf16 streamer.
// 128x64 tile, wave=32x64 (acc[2][4]), 24 KiB LDS -> 6 blocks/CU. HBM-bound (~102 MB read).
__global__ __launch_bounds__(256) void gemm2_k(
    const ushort_t* __restrict__ AHi, const ushort_t* __restrict__ ALo,
    const ushort_t* __restrict__ BtHi, const ushort_t* __restrict__ BtLo,
    _Float16* __restrict__ C)
{
    const int M = NN, N = OUTD, K = HIDD;
    __shared__ __align__(16) ushort_t sAh[128 * 32];   // 8 KiB each, swizzled
    __shared__ __align__(16) ushort_t sAl[128 * 32];
    __shared__ __align__(16) ushort_t sBh[64 * 32];    // 4 KiB each
    __shared__ __align__(16) ushort_t sBl[64 * 32];

    const int tid  = threadIdx.x;
    const int wave = tid >> 6;
    const int lane = tid & 63;
    const int quad = lane >> 4;
    const int l15  = lane & 15;
    const int m0   = blockIdx.x * 128;

    const ushort_t* ahSrc[2]; const ushort_t* alSrc[2];
    ushort_t* ahDst[2]; ushort_t* alDst[2];
    #pragma unroll
    for (int it = 0; it < 2; ++it) {
        int f = it * 256 + tid;          // block 0..511
        int r = f >> 2;
        int qp = (f & 3) ^ ((r >> 1) & 3);
        int gr = m0 + r; if (gr >= M) gr = M - 1;
        ahSrc[it] = AHi + (size_t)gr * K + qp * 8;
        alSrc[it] = ALo + (size_t)gr * K + qp * 8;
        ahDst[it] = &sAh[f * 8];
        alDst[it] = &sAl[f * 8];
    }
    const ushort_t *bhSrc, *blSrc; ushort_t *bhDst, *blDst;
    {
        int f = tid;                     // block 0..255 (64 rows x 4 blocks)
        int r = f >> 2;
        int qp = (f & 3) ^ ((r >> 1) & 3);
        bhSrc = BtHi + (size_t)r * K + qp * 8;
        blSrc = BtLo + (size_t)r * K + qp * 8;
        bhDst = &sBh[f * 8];
        blDst = &sBl[f * 8];
    }

    int aOff[2], bOff[4];
    #pragma unroll
    for (int ms = 0; ms < 2; ++ms) {
        int rA = wave * 32 + ms * 16 + l15;
        aOff[ms] = rA * 32 + (quad ^ ((rA >> 1) & 3)) * 8;
    }
    #pragma unroll
    for (int ns = 0; ns < 4; ++ns) {
        int rB = ns * 16 + l15;
        bOff[ns] = rB * 32 + (quad ^ ((rB >> 1) & 3)) * 8;
    }

    f32x4 acc[2][4] = {};

    for (int k0 = 0; k0 < K; k0 += 32) {
        #pragma unroll
        for (int it = 0; it < 2; ++it) {
            GLOAD_LDS16(ahSrc[it] + k0, ahDst[it]);
            GLOAD_LDS16(alSrc[it] + k0, alDst[it]);
        }
        GLOAD_LDS16(bhSrc + k0, bhDst);
        GLOAD_LDS16(blSrc + k0, blDst);
        __syncthreads();

        bf16x8 aH[2], aL[2];
        #pragma unroll
        for (int ms = 0; ms < 2; ++ms) {
            aH[ms] = *(const bf16x8*)&sAh[aOff[ms]];
            aL[ms] = *(const bf16x8*)&sAl[aOff[ms]];
        }
        #pragma unroll
        for (int ns = 0; ns < 4; ++ns) {
            bf16x8 bH = *(const bf16x8*)&sBh[bOff[ns]];
            bf16x8 bL = *(const bf16x8*)&sBl[bOff[ns]];
            #pragma unroll
            for (int ms = 0; ms < 2; ++ms) {
                acc[ms][ns] = __builtin_amdgcn_mfma_f32_16x16x32_bf16(aH[ms], bH, acc[ms][ns], 0, 0, 0);
                acc[ms][ns] = __builtin_amdgcn_mfma_f32_16x16x32_bf16(aL[ms], bH, acc[ms][ns], 0, 0, 0);
                acc[ms][ns] = __builtin_amdgcn_mfma_f32_16x16x32_bf16(aH[ms], bL, acc[ms][ns], 0, 0, 0);
            }
        }
        __syncthreads();
    }

    #pragma unroll
    for (int ms = 0; ms < 2; ++ms) {
        int row = m0 + wave * 32 + ms * 16 + quad * 4;
        #pragma unroll
        for (int ns = 0; ns < 4; ++ns) {
            int col = ns * 16 + l15;
            #pragma unroll
            for (int r = 0; r < 4; ++r)
                if (row + r < M) C[(size_t)(row + r) * N + col] = (_Float16)acc[ms][ns][r];
        }
    }
}

// ---------------------------------------------------------------- CSR build (binned)
__global__ __launch_bounds__(256) void bhist_k(const int* __restrict__ dst,
                                               int* __restrict__ bucketHist) {
    __shared__ int h[NBKT];
    int t = threadIdx.x;
    if (t < NBKT) h[t] = 0;
    __syncthreads();
    #pragma unroll
    for (int j = 0; j < 4; ++j) {
        int e = blockIdx.x * 1024 + t + j * 256;
        if (e < NE) atomicAdd(&h[dst[e] >> 10], 1);
    }
    __syncthreads();
    if (t < NBKT && h[t]) atomicAdd(&bucketHist[t], h[t]);
}

__global__ __launch_bounds__(128) void bscan_k(const int* __restrict__ bucketHist,
                                               int* __restrict__ bucketStart,
                                               int* __restrict__ bucketCursor) {
    __shared__ int s[128];
    int t = threadIdx.x;
    int v = (t < NBKT) ? bucketHist[t] : 0;
    s[t] = v;
    for (int off = 1; off < 128; off <<= 1) {
        __syncthreads();
        int a = (t >= off) ? s[t - off] : 0;
        __syncthreads();
        s[t] += a;
    }
    __syncthreads();
    if (t < NBKT) { bucketStart[t] = s[t] - v; bucketCursor[t] = s[t] - v; }
    if (t == NBKT - 1) bucketStart[NBKT] = s[t];
}

__global__ __launch_bounds__(256) void phase1_k(
    const int* __restrict__ src, const int* __restrict__ dst,
    const float* __restrict__ w, int* __restrict__ bucketCursor,
    int2* __restrict__ binned)
{
    __shared__ int2 raw[P1E];
    __shared__ int2 ord[P1E];
    __shared__ ushort_t rbkt[P1E], obkt[P1E];
    __shared__ int hist[128], excl[128], cursor[128], gbase[128], stmp[128];

    int t = threadIdx.x;
    if (t < 128) hist[t] = 0;
    __syncthreads();

    int e0 = blockIdx.x * P1E;
    #pragma unroll
    for (int j = 0; j < P1E / 256; ++j) {
        int li = t + j * 256;
        int e = e0 + li;
        if (e < NE) {
            int d = dst[e];
            int b = d >> 10;
            raw[li] = make_int2(src[e] | ((d & 1023) << 17), __float_as_int(w[e]));
            rbkt[li] = (ushort_t)b;
            atomicAdd(&hist[b], 1);
        } else rbkt[li] = 0xFFFFu;
    }
    __syncthreads();
    int v = (t < 128) ? hist[t] : 0;
    if (t < 128) stmp[t] = v;
    for (int off = 1; off < 128; off <<= 1) {
        __syncthreads();
        int a = (t < 128 && t >= off) ? stmp[t - off] : 0;
        __syncthreads();
        if (t < 128) stmp[t] += a;
    }
    __syncthreads();
    if (t < 128) { excl[t] = stmp[t] - v; cursor[t] = stmp[t] - v; }
    if (t < NBKT) gbase[t] = atomicAdd(&bucketCursor[t], hist[t]);
    __syncthreads();
    #pragma unroll
    for (int j = 0; j < P1E / 256; ++j) {
        int li = t + j * 256;
        ushort_t b = rbkt[li];
        if (b != 0xFFFFu) {
            int p = atomicAdd(&cursor[b], 1);
            ord[p] = raw[li];
            obkt[p] = b;
        }
    }
    __syncthreads();
    int tot = excl[NBKT - 1] + hist[NBKT - 1];
    #pragma unroll
    for (int j = 0; j < P1E / 256; ++j) {
        int li = t + j * 256;
        if (li < tot) {
            int b = obkt[li];
            binned[(size_t)gbase[b] + (li - excl[b])] = ord[li];
        }
    }
}

__global__ __launch_bounds__(256) void phase2_k(
    const int* __restrict__ bucketStart, const int2* __restrict__ binned,
    int* __restrict__ rowptr, int2* __restrict__ esw)
{
    __shared__ int cnt[1024], ex[1024], cur[1024], wsum[256];
    int t = threadIdx.x, blk = blockIdx.x;
    int gb = bucketStart[blk], ge = bucketStart[blk + 1];
    #pragma unroll
    for (int j = 0; j < 4; ++j) cnt[t + j * 256] = 0;
    __syncthreads();
    for (int e = gb + t; e < ge; e += 256)
        atomicAdd(&cnt[(binned[e].x >> 17) & 1023], 1);
    __syncthreads();
    int b4 = t * 4;
    int l0 = cnt[b4], l1 = cnt[b4 + 1], l2 = cnt[b4 + 2], l3 = cnt[b4 + 3];
    int ls = l0 + l1 + l2 + l3;
    wsum[t] = ls;
    for (int off = 1; off < 256; off <<= 1) {
        __syncthreads();
        int a = (t >= off) ? wsum[t - off] : 0;
        __syncthreads();
        wsum[t] += a;
    }
    __syncthreads();
    int be = wsum[t] - ls;
    ex[b4] = be;            cur[b4] = be;
    ex[b4 + 1] = be + l0;     cur[b4 + 1] = be + l0;
    ex[b4 + 2] = be + l0 + l1;  cur[b4 + 2] = be + l0 + l1;
    ex[b4 + 3] = be + l0 + l1 + l2; cur[b4 + 3] = be + l0 + l1 + l2;
    __syncthreads();
    int n0 = blk << 10;
    #pragma unroll
    for (int j = 0; j < 4; ++j) {
        int i = b4 + j;
        if (n0 + i < NN) rowptr[n0 + i] = gb + ex[i];
    }
    if (blk == NBKT - 1 && t == 0) rowptr[NN] = NE;
    for (int e = gb + t; e < ge; e += 256) {
        int2 en = binned[e];
        int d = (en.x >> 17) & 1023;
        int p = atomicAdd(&cur[d], 1);
        esw[(size_t)gb + p] = make_int2(en.x & 0x1FFFF, en.y);
    }
}

// ---------------------------------------------------------------- SpMM layer 1 (+ReLU)
// one wave per node, lane owns 4 features. Epilogue now writes the layer-2 A operand
// PRE-SPLIT as bf16 hi/lo (RTNE both — bit-identical to the old in-GEMM split of f32 h),
// same total bytes as the old f32 h.
__global__ __launch_bounds__(256) void spmm_relu_k(
    const int* __restrict__ rowptr, const int2* __restrict__ esw,
    const _Float16* __restrict__ X, ushort_t* __restrict__ Hhi,
    ushort_t* __restrict__ Hlo)
{
    const int wave = threadIdx.x >> 6;
    const int lane = threadIdx.x & 63;
    const int node = blockIdx.x * 4 + wave;
    const int beg = rowptr[node], end = rowptr[node + 1];
    f32x4 acc = {0.f, 0.f, 0.f, 0.f};
    const _Float16* Xl = X + lane * 4;
    #pragma unroll 8
    for (int e = beg; e < end; ++e) {
        int2 sw = esw[e];
        float w = __int_as_float(sw.y);
        f16x4 v = *(const f16x4*)(Xl + (size_t)sw.x * HIDD);
        acc.x += (float)v[0] * w;
        acc.y += (float)v[1] * w;
        acc.z += (float)v[2] * w;
        acc.w += (float)v[3] * w;
    }
    float vals[4] = {fmaxf(acc.x, 0.f), fmaxf(acc.y, 0.f),
                     fmaxf(acc.z, 0.f), fmaxf(acc.w, 0.f)};
    U4 H, L;
    #pragma unroll
    for (int j = 0; j < 4; ++j) {
        ushort_t h = f2bf(vals[j]);
        H.us[j] = h;
        L.us[j] = f2bf(vals[j] - bf2f(h));
    }
    *(uint2*)(Hhi + (size_t)node * HIDD + lane * 4) = H.v;
    *(uint2*)(Hlo + (size_t)node * HIDD + lane * 4) = L.v;
}

// ---------------------------------------------------------------- SpMM layer 2 + softmax
// one wave per node; lane = feature (64). fp16 gather table.
__global__ __launch_bounds__(256) void spmm_softmax_k(
    const int* __restrict__ rowptr, const int2* __restrict__ esw,
    const _Float16* __restrict__ X, float* __restrict__ out)
{
    int node = blockIdx.x * 4 + (threadIdx.x >> 6);
    int lane = threadIdx.x & 63;
    int beg = rowptr[node], end = rowptr[node + 1];
    float acc = 0.f;
    #pragma unroll 4
    for (int e = beg; e < end; ++e) {
        int2 sw = esw[e];
        acc += __int_as_float(sw.y) * (float)X[(size_t)sw.x * OUTD + lane];
    }
    float mx = acc;
    #pragma unroll
    for (int off = 32; off > 0; off >>= 1) mx = fmaxf(mx, __shfl_xor(mx, off));
    float ex = __expf(acc - mx);
    float sm = ex;
    #pragma unroll
    for (int off = 32; off > 0; off >>= 1) sm += __shfl_xor(sm, off);
    out[(size_t)node * OUTD + lane] = ex / sm;
}

// ---------------------------------------------------------------- launch
extern "C" void kernel_launch(void* const* d_in, const int* in_sizes, int n_in,
                              void* d_out, int out_size, void* d_ws, size_t ws_size,
                              hipStream_t stream) {
    const float* x  = (const float*)d_in[0];
    const int*   ei = (const int*)d_in[1];
    const float* ew = (const float*)d_in[2];
    const float* W1 = (const float*)d_in[3];
    const float* W2 = (const float*)d_in[4];
    float* out = (float*)d_out;
    const int* src = ei;        // edge_index row 0
    const int* dst = ei + NE;   // edge_index row 1

    char* ws = (char*)d_ws;
    size_t o = 0;
    auto take = [&](size_t bytes) -> void* {
        void* p = (void*)(ws + o);
        o += (bytes + 255) & ~(size_t)255;
        return p;
    };
    _Float16* S1      = (_Float16*)take((size_t)NN * HIDD * 2);   // 51.2 MB fp16 (reused as S2)
    ushort_t* hHi     = (ushort_t*)take((size_t)NN * HIDD * 2);   // 51.2 MB (binned aliases it)
    ushort_t* hLo     = (ushort_t*)take((size_t)NN * HIDD * 2);   // 51.2 MB
    ushort_t* W1tHi   = (ushort_t*)take((size_t)IND * HIDD * 2);
    ushort_t* W1tLo   = (ushort_t*)take((size_t)IND * HIDD * 2);
    ushort_t* W2tHi   = (ushort_t*)take((size_t)HIDD * OUTD * 2);
    ushort_t* W2tLo   = (ushort_t*)take((size_t)HIDD * OUTD * 2);
    int*      rowptr  = (int*     )take((size_t)(NN + 1) * 4);
    int*      bHist   = (int*     )take(NBKT * 4);
    int*      bStart  = (int*     )take((NBKT + 1) * 4);
    int*      bCursor = (int*     )take(NBKT * 4);
    int2*     esw     = (int2*    )take((size_t)NE * 8);          // 25.6 MB
    int2*     binned  = (int2*)hHi;                               // alias: hHi written later
    _Float16* S2      = S1;                                       // alias: S1 dead after spmm1
    (void)in_sizes; (void)n_in; (void)out_size; (void)ws_size;

    const int MB = (NN + 127) / 128;          // 782

    hipMemsetAsync(bHist, 0, NBKT * 4, stream);
    splitw_k<<<(IND * HIDD + 255) / 256, 256, 0, stream>>>(W1, W1tHi, W1tLo, IND, HIDD);
    splitw_k<<<(HIDD * OUTD + 255) / 256, 256, 0, stream>>>(W2, W2tHi, W2tLo, HIDD, OUTD);

    // CSR build: bucket hist -> scan -> bin -> per-bucket node sort
    bhist_k<<<(NE + 1023) / 1024, 256, 0, stream>>>(dst, bHist);
    bscan_k<<<1, 128, 0, stream>>>(bHist, bStart, bCursor);
    phase1_k<<<(NE + P1E - 1) / P1E, 256, 0, stream>>>(src, dst, ew, bCursor, binned);
    phase2_k<<<NBKT, 256, 0, stream>>>(bStart, binned, rowptr, esw);

    // layer 1: S1 = x @ W1 (split-bf16 3-MFMA, global_load_lds staging, fp16 out)
    gemm1_k<<<dim3(2, MB), 256, 0, stream>>>(x, W1tHi, W1tLo, S1);
    // h (split bf16 hi/lo) = relu(A_sp @ S1), single pass (fp16 gather, 8 B/lane)
    spmm_relu_k<<<NN / 4, 256, 0, stream>>>(rowptr, esw, S1, hHi, hLo);
    // layer 2: S2 = h @ W2 (pure-bf16 split GEMM, fp16 out), out = softmax(A_sp @ S2)
    gemm2_k<<<MB, 256, 0, stream>>>(hHi, hLo, W2tHi, W2tLo, S2);
    spmm_softmax_k<<<NN / 4, 256, 0, stream>>>(rowptr, esw, S2, out);
}